// Round 18
// baseline (131.360 us; speedup 1.0000x reference)
//
#include <hip/hip_runtime.h>

#define S_LEN 8192
#define D_DIM 2048
#define HD    128
#define KVB   32       // kv tile rows
#define NCH   16       // kv chunks (flash-decoding split)
#define QTR   256      // q rows per block tile (8 waves x 32)

typedef __attribute__((ext_vector_type(8))) short bf16x8;
typedef __attribute__((ext_vector_type(4))) float f32x4;

__device__ __forceinline__ unsigned short f2bf(float f) {
  unsigned int u = __float_as_uint(f);
  u += 0x7fffu + ((u >> 16) & 1u);
  return (unsigned short)(u >> 16);
}
__device__ __forceinline__ float bf2f(unsigned short h) {
  return __uint_as_float(((unsigned int)h) << 16);
}

__device__ __forceinline__ void glds16(const void* g, const short* l) {
  __builtin_amdgcn_global_load_lds(
      (const __attribute__((address_space(1))) void*)g,
      (__attribute__((address_space(3))) void*)l, 16, 0, 0);
}

// ---------------- transpose+split w: wT[mode][col][k] hi/lo bf16 ----------------
__global__ __launch_bounds__(256)
void split_w_kernel(const float* __restrict__ wq, const float* __restrict__ wk,
                    const float* __restrict__ wv,
                    unsigned short* __restrict__ wTh, unsigned short* __restrict__ wTl)
{
  const int mode = blockIdx.y;
  const float* __restrict__ w = (mode == 0) ? wq : (mode == 1) ? wk : wv;
  unsigned short* __restrict__ oh = wTh + (size_t)mode * HD * D_DIM;
  unsigned short* __restrict__ ol = wTl + (size_t)mode * HD * D_DIM;
  const int k0 = blockIdx.x * 64;

  __shared__ float ws[64][132];
  const int t = threadIdx.x;
#pragma unroll
  for (int i = 0; i < 8; ++i) {
    int idx = t + i * 256;
    int row = idx >> 5;
    int c4  = idx & 31;
    *(float4*)&ws[row][c4 * 4] = *(const float4*)(w + (size_t)(k0 + row) * HD + c4 * 4);
  }
  __syncthreads();
#pragma unroll
  for (int i = 0; i < 4; ++i) {
    int task = t + i * 256;
    int col = task >> 3;
    int kc  = task & 7;
    ushort4 h[2], l[2];
#pragma unroll
    for (int e = 0; e < 8; ++e) {
      float f = ws[kc * 8 + e][col];
      unsigned short hb = f2bf(f);
      ((unsigned short*)&h[e >> 2])[e & 3] = hb;
      ((unsigned short*)&l[e >> 2])[e & 3] = f2bf(f - bf2f(hb));
    }
    size_t off = (size_t)col * D_DIM + k0 + kc * 8;
    *(ushort4*)(oh + off)     = h[0];
    *(ushort4*)(oh + off + 4) = h[1];
    *(ushort4*)(ol + off)     = l[0];
    *(ushort4*)(ol + off + 4) = l[1];
  }
}

// ---------------- projection GEMM, split-K, sibling-grouped 1D grid ----------------
// bid -> mt = bid/6, mode = (bid%6)>>1, kz = bid&1: the 6 blocks sharing an x-tile are
// consecutive -> co-resident -> x fetched ~once from HBM (L2/L3 hits for siblings).
__global__ __launch_bounds__(256)
void proj_sk_kernel(const float* __restrict__ x,
                    const unsigned short* __restrict__ wTh, const unsigned short* __restrict__ wTl,
                    float* __restrict__ pp)
{
  __shared__ short sm[2][12288];

  const int bid  = blockIdx.x;
  const int mt   = bid / 6;
  const int rem  = bid % 6;
  const int mode = rem >> 1;
  const int kz   = rem & 1;
  const bool split = (mode < 2);
  const int kbase = kz * (D_DIM / 2);

  const unsigned short* gwh = wTh + (size_t)mode * HD * D_DIM + kbase;
  const unsigned short* gwl = wTl + (size_t)mode * HD * D_DIM + kbase;

  const int t   = threadIdx.x;
  const int wid = t >> 6;
  const int ln  = t & 63;
  const int cl  = ln & 15;
  const int g4  = ln >> 4;

  const int slotx = wid * 64 + ln;          // 0..255
  const int rowx  = slotx >> 2, scx = slotx & 3;
  const int kofx  = (scx ^ (rowx & 3)) * 8;
  const float* gx = x + (size_t)(mt * 64 + rowx) * D_DIM + kbase + kofx;

  auto stagew = [&](int kt, int buf) {
    short* b = sm[buf];
#pragma unroll
    for (int g = 0; g < 2; ++g) {
      int slot = g * 256 + wid * 64 + ln;
      int col = slot >> 2, sc = slot & 3;
      int kof = (sc ^ (col & 3)) * 8;
      glds16(gwh + (size_t)col * D_DIM + kt + kof, b + 4096 + (g * 256 + wid * 64) * 8);
      if (split)
        glds16(gwl + (size_t)col * D_DIM + kt + kof, b + 8192 + (g * 256 + wid * 64) * 8);
    }
  };
  auto writex = [&](const float4& a0, const float4& a1, int buf) {
    short* b = sm[buf];
    float fv[8];
    *(float4*)&fv[0] = a0;
    *(float4*)&fv[4] = a1;
    bf16x8 hv, lv;
#pragma unroll
    for (int e = 0; e < 8; ++e) {
      unsigned short hb = f2bf(fv[e]);
      hv[e] = (short)hb;
      lv[e] = (short)f2bf(fv[e] - bf2f(hb));
    }
    *(bf16x8*)(b + slotx * 8) = hv;
    if (split) *(bf16x8*)(b + 2048 + slotx * 8) = lv;
  };

  f32x4 acc[2][4];
#pragma unroll
  for (int m = 0; m < 2; ++m)
#pragma unroll
    for (int n = 0; n < 4; ++n) acc[m][n] = f32x4{0.f, 0.f, 0.f, 0.f};

  {
    float4 a0 = *(const float4*)(gx + 0);
    float4 a1 = *(const float4*)(gx + 4);
    stagew(0, 0);
    writex(a0, a1, 0);
  }
  __syncthreads();

  const int KHALF = D_DIM / 2;
  for (int kt = 0, step = 0; kt < KHALF; kt += 32, ++step) {
    const int cur = step & 1;
    const bool more = (kt + 32 < KHALF);
    float4 n0, n1;
    if (more) {
      n0 = *(const float4*)(gx + kt + 32);
      n1 = *(const float4*)(gx + kt + 36);
      stagew(kt + 32, cur ^ 1);
    }

    const short* b = sm[cur];
    bf16x8 a_h[2], a_l[2], b_h[4], b_l[4];
#pragma unroll
    for (int m = 0; m < 2; ++m) {
      int row = (wid >> 1) * 32 + m * 16 + cl;
      int byte = row * 64 + ((g4 ^ (row & 3)) << 4);
      a_h[m] = *(const bf16x8*)((const char*)b + byte);
      if (split) a_l[m] = *(const bf16x8*)((const char*)b + 4096 + byte);
    }
#pragma unroll
    for (int n = 0; n < 4; ++n) {
      int col = (wid & 1) * 64 + n * 16 + cl;
      int byte = col * 64 + ((g4 ^ (col & 3)) << 4);
      b_h[n] = *(const bf16x8*)((const char*)b + 8192 + byte);
      if (split) b_l[n] = *(const bf16x8*)((const char*)b + 16384 + byte);
    }

#pragma unroll
    for (int m = 0; m < 2; ++m)
#pragma unroll
      for (int n = 0; n < 4; ++n)
        acc[m][n] = __builtin_amdgcn_mfma_f32_16x16x32_bf16(a_h[m], b_h[n], acc[m][n], 0, 0, 0);
    if (split) {
#pragma unroll
      for (int m = 0; m < 2; ++m)
#pragma unroll
        for (int n = 0; n < 4; ++n) {
          acc[m][n] = __builtin_amdgcn_mfma_f32_16x16x32_bf16(a_l[m], b_h[n], acc[m][n], 0, 0, 0);
          acc[m][n] = __builtin_amdgcn_mfma_f32_16x16x32_bf16(a_h[m], b_l[n], acc[m][n], 0, 0, 0);
        }
    }
    if (more) writex(n0, n1, cur ^ 1);
    __syncthreads();
  }

  // fp32 partial to pp[(mode*2 + kz)][row][col]
  const int rbase = mt * 64 + (wid >> 1) * 32 + g4 * 4;
  const int cbase = (wid & 1) * 64 + cl;
  float* op = pp + ((size_t)(mode * 2 + kz)) * S_LEN * HD;
#pragma unroll
  for (int m = 0; m < 2; ++m)
#pragma unroll
    for (int n = 0; n < 4; ++n)
#pragma unroll
      for (int r = 0; r < 4; ++r)
        op[(size_t)(rbase + m * 16 + r) * HD + cbase + n * 16] = acc[m][n][r];
}

// ---------------- reduce split-K partials + split/scale/transpose epilogue ----------------
__global__ __launch_bounds__(256)
void reduce_split_kernel(const float* __restrict__ pp,
                         unsigned short* __restrict__ q_hi, unsigned short* __restrict__ q_lo,
                         unsigned short* __restrict__ k_hi, unsigned short* __restrict__ k_lo,
                         unsigned short* __restrict__ vT)
{
  __shared__ float tile[64][132];
  const int mode = blockIdx.y;
  const int mt   = blockIdx.x;
  const int t    = threadIdx.x;

  const float* p0 = pp + ((size_t)(mode * 2 + 0)) * S_LEN * HD + (size_t)mt * 64 * HD;
  const float* p1 = pp + ((size_t)(mode * 2 + 1)) * S_LEN * HD + (size_t)mt * 64 * HD;

  if (mode < 2) {
    const float scale = (mode == 0) ? 0.08838834764831843f : 1.0f;
    unsigned short* __restrict__ oh = (mode == 0) ? q_hi : k_hi;
    unsigned short* __restrict__ ol = (mode == 0) ? q_lo : k_lo;
#pragma unroll
    for (int i = 0; i < 8; ++i) {
      int off = i * 1024 + t * 4;
      float4 a = *(const float4*)(p0 + off);
      float4 b = *(const float4*)(p1 + off);
      ushort4 hv, lv;
#pragma unroll
      for (int e = 0; e < 4; ++e) {
        float s = (((const float*)&a)[e] + ((const float*)&b)[e]) * scale;
        unsigned short hb = f2bf(s);
        ((unsigned short*)&hv)[e] = hb;
        ((unsigned short*)&lv)[e] = f2bf(s - bf2f(hb));
      }
      int row = off >> 7, col = off & 127;
      size_t go = (size_t)(mt * 64 + row) * HD + col;
      *(ushort4*)(oh + go) = hv;
      *(ushort4*)(ol + go) = lv;
    }
  } else {
#pragma unroll
    for (int i = 0; i < 8; ++i) {
      int off = i * 1024 + t * 4;
      float4 a = *(const float4*)(p0 + off);
      float4 b = *(const float4*)(p1 + off);
      int row = off >> 7, col = off & 127;
      float4 s;
      s.x = a.x + b.x; s.y = a.y + b.y; s.z = a.z + b.z; s.w = a.w + b.w;
      *(float4*)&tile[row][col] = s;
    }
    __syncthreads();
    const int col = t >> 1, half = t & 1;
#pragma unroll
    for (int r8 = 0; r8 < 4; ++r8) {
      bf16x8 v;
#pragma unroll
      for (int e = 0; e < 8; ++e)
        v[e] = (short)f2bf(tile[half * 32 + r8 * 8 + e][col]);
      *(bf16x8*)(vT + (size_t)col * S_LEN + mt * 64 + half * 32 + r8 * 8) = v;
    }
  }
}

// ---------------- MFMA flash attention v6b (r14 best): 8-wave block, Q-lo in LDS ----------------
__global__ __launch_bounds__(512)
void attn_kernel(const unsigned short* __restrict__ q_hi, const unsigned short* __restrict__ q_lo,
                 const unsigned short* __restrict__ k_hi, const unsigned short* __restrict__ k_lo,
                 const unsigned short* __restrict__ vT,
                 unsigned short* __restrict__ part_o, float* __restrict__ part_ml)
{
  extern __shared__ short smem[];
  short* ls_kh = smem;               // 2 x 4096: K hi 32x128, swizzled (sc ^ row&7)
  short* ls_kl = ls_kh + 8192;       // 2 x 4096: K lo
  short* ls_v  = ls_kl + 8192;       // 2 x 4096: v^T 128x32, swizzled (sub ^ (d>>1)&3)
  short* ls_ql = ls_v + 8192;        // 256 x 128: Q lo tile, swizzled like K
  short* ls_p  = ls_ql + 32768;      // 8 waves x [32][40]

  const int t   = threadIdx.x;
  const int wid = t >> 6;            // 0..7
  const int ln  = t & 63;
  const int cl  = ln & 15;
  const int g4  = ln >> 4;
  const int pairId = blockIdx.x >> 4;   // 0..15
  const int chunk  = blockIdx.x & 15;

  short* pw = ls_p + wid * 1280;

  auto stage = [&](int j, int buf) {
    const unsigned short* gkh = k_hi + (size_t)j * KVB * HD;
    const unsigned short* gkl = k_lo + (size_t)j * KVB * HD;
    const unsigned short* gv  = vT + (size_t)j * KVB;
    {
      int row = t >> 4, sc = t & 15;          // 512 slots = 32 rows x 16
      int c16 = sc ^ (row & 7);
      glds16(gkh + row * HD + c16 * 8, ls_kh + buf * 4096 + t * 8);
      glds16(gkl + row * HD + c16 * 8, ls_kl + buf * 4096 + t * 8);
    }
    {
      int d = t >> 2, sub = t & 3;            // 512 slots = 128 d x 4
      int s2 = sub ^ ((d >> 1) & 3);
      glds16(gv + (size_t)d * S_LEN + s2 * 8, ls_v + buf * 4096 + t * 8);
    }
  };

  for (int hh = 0; hh < 2; ++hh) {
    const int T = hh ? (31 - pairId) : pairId;
    const int jmaxB = 8 * T + 7;
    const int jmaxW = 8 * T + wid;
    const int rowbase = T * QTR + wid * 32;

    // stage Q-lo tile (256x128 bf16, 64KB); consumed only after the in-loop barrier
    {
      const unsigned short* gql = q_lo + (size_t)T * QTR * HD;
#pragma unroll
      for (int i = 0; i < 8; ++i) {
        int slot = i * 512 + t;
        int row = slot >> 4, sc = slot & 15;
        int c16 = sc ^ (row & 7);
        glds16(gql + (size_t)row * HD + c16 * 8, ls_ql + slot * 8);
      }
    }

    // Q-hi fragments in registers (A-layout: row = rg*16 + cl, k = kc*32 + g4*8 + e)
    bf16x8 qh[2][4];
#pragma unroll
    for (int rg = 0; rg < 2; ++rg) {
      const size_t qoff = ((size_t)rowbase + rg * 16 + cl) * HD + g4 * 8;
#pragma unroll
      for (int kc = 0; kc < 4; ++kc)
        qh[rg][kc] = *(const bf16x8*)(q_hi + qoff + kc * 32);
    }

    float m_i[2][4], l_i[2][4];
    f32x4 o_acc[2][8];
#pragma unroll
    for (int rg = 0; rg < 2; ++rg)
#pragma unroll
      for (int i = 0; i < 4; ++i) { m_i[rg][i] = -1e30f; l_i[rg][i] = 0.f; }
#pragma unroll
    for (int rg = 0; rg < 2; ++rg)
#pragma unroll
      for (int c2 = 0; c2 < 8; ++c2) o_acc[rg][c2] = f32x4{0.f, 0.f, 0.f, 0.f};

    if (chunk <= jmaxB) {
      int cur = 0;
      stage(chunk, 0);
      __syncthreads();
      for (int j = chunk; j <= jmaxB; j += NCH) {
        if (j + NCH <= jmaxB) stage(j + NCH, cur ^ 1);

        if (j <= jmaxW) {
          const int rl0 = wid * 32 + cl;       // local tile row, rg = 0
          const int rl1 = rl0 + 16;            // rg = 1 (same &7 as rl0)
          // ---- QK^T: 3-product split (hh + lh + hl); Q-lo frags from LDS
          f32x4 s[2][2];
          s[0][0] = f32x4{0.f, 0.f, 0.f, 0.f};
          s[0][1] = f32x4{0.f, 0.f, 0.f, 0.f};
          s[1][0] = f32x4{0.f, 0.f, 0.f, 0.f};
          s[1][1] = f32x4{0.f, 0.f, 0.f, 0.f};
          __builtin_amdgcn_s_setprio(1);
#pragma unroll
          for (int kc = 0; kc < 4; ++kc) {
            const int ch = kc * 4 + g4;
            bf16x8 ql0 = *(const bf16x8*)((const char*)ls_ql + rl0 * 256 + ((ch ^ (rl0 & 7)) << 4));
            bf16x8 ql1 = *(const bf16x8*)((const char*)ls_ql + rl1 * 256 + ((ch ^ (rl1 & 7)) << 4));
#pragma unroll
            for (int c = 0; c < 2; ++c) {
              const int kcol = c * 16 + cl;
              const int byteK = kcol * 256 + ((ch ^ (kcol & 7)) << 4);
              bf16x8 khf = *(const bf16x8*)((const char*)(ls_kh + cur * 4096) + byteK);
              bf16x8 klf = *(const bf16x8*)((const char*)(ls_kl + cur * 4096) + byteK);
              s[0][c] = __builtin_amdgcn_mfma_f32_16x16x32_bf16(qh[0][kc], khf, s[0][c], 0, 0, 0);
              s[0][c] = __builtin_amdgcn_mfma_f32_16x16x32_bf16(ql0,      khf, s[0][c], 0, 0, 0);
              s[0][c] = __builtin_amdgcn_mfma_f32_16x16x32_bf16(qh[0][kc], klf, s[0][c], 0, 0, 0);
              s[1][c] = __builtin_amdgcn_mfma_f32_16x16x32_bf16(qh[1][kc], khf, s[1][c], 0, 0, 0);
              s[1][c] = __builtin_amdgcn_mfma_f32_16x16x32_bf16(ql1,      khf, s[1][c], 0, 0, 0);
              s[1][c] = __builtin_amdgcn_mfma_f32_16x16x32_bf16(qh[1][kc], klf, s[1][c], 0, 0, 0);
            }
          }
          __builtin_amdgcn_s_setprio(0);

          // causal mask: only the wave's diagonal kv tile crosses row boundaries
          if (j == jmaxW) {
#pragma unroll
            for (int rg = 0; rg < 2; ++rg)
#pragma unroll
              for (int c = 0; c < 2; ++c)
#pragma unroll
                for (int i = 0; i < 4; ++i) {
                  int col = j * KVB + c * 16 + cl;
                  int row = rowbase + rg * 16 + g4 * 4 + i;
                  if (col > row) s[rg][c][i] = -1e30f;
                }
          }

          // ---- defer-max online softmax (shuffle-free steady state)
          bool ok = true;
#pragma unroll
          for (int rg = 0; rg < 2; ++rg)
#pragma unroll
            for (int i = 0; i < 4; ++i) {
              float mx = fmaxf(s[rg][0][i], s[rg][1][i]);
              ok = ok && (mx <= m_i[rg][i] + 8.0f);
            }
          if (!__all(ok)) {
#pragma unroll
            for (int rg = 0; rg < 2; ++rg)
#pragma unroll
              for (int i = 0; i < 4; ++i) {
                float rm = fmaxf(s[rg][0][i], s[rg][1][i]);
                rm = fmaxf(rm, __shfl_xor(rm, 1));
                rm = fmaxf(rm, __shfl_xor(rm, 2));
                rm = fmaxf(rm, __shfl_xor(rm, 4));
                rm = fmaxf(rm, __shfl_xor(rm, 8));
                float mnew = fmaxf(m_i[rg][i], rm);
                float corr = __expf(m_i[rg][i] - mnew);
                l_i[rg][i] *= corr;
#pragma unroll
                for (int c2 = 0; c2 < 8; ++c2) o_acc[rg][c2][i] *= corr;
                m_i[rg][i] = mnew;
              }
          }

          // p = exp(s - m) (0 for masked), lane-partial l, P -> wave LDS (bf16)
#pragma unroll
          for (int rg = 0; rg < 2; ++rg)
#pragma unroll
            for (int c = 0; c < 2; ++c)
#pragma unroll
              for (int i = 0; i < 4; ++i) {
                float sv = s[rg][c][i];
                float p = (sv > -1e29f) ? __expf(sv - m_i[rg][i]) : 0.f;
                l_i[rg][i] += p;
                pw[(rg * 16 + g4 * 4 + i) * 40 + c * 16 + cl] = (short)f2bf(p);
              }

          // ---- PV: o += P @ V (A-frags from wave LDS, B-frags = vT rows, shared by rg)
          bf16x8 pa0 = *(const bf16x8*)((const char*)pw + cl * 80 + g4 * 16);
          bf16x8 pa1 = *(const bf16x8*)((const char*)pw + (16 + cl) * 80 + g4 * 16);
          __builtin_amdgcn_s_setprio(1);
#pragma unroll
          for (int c2 = 0; c2 < 8; ++c2) {
            const int d0 = c2 * 16 + cl;
            const int byteV = d0 * 64 + ((g4 ^ ((d0 >> 1) & 3)) << 4);
            bf16x8 vb = *(const bf16x8*)((const char*)(ls_v + cur * 4096) + byteV);
            o_acc[0][c2] = __builtin_amdgcn_mfma_f32_16x16x32_bf16(pa0, vb, o_acc[0][c2], 0, 0, 0);
            o_acc[1][c2] = __builtin_amdgcn_mfma_f32_16x16x32_bf16(pa1, vb, o_acc[1][c2], 0, 0, 0);
          }
          __builtin_amdgcn_s_setprio(0);
        }

        __syncthreads();
        cur ^= 1;
      }
    }

    // ---- write partials as bf16 (unconditional; zeros + m=-1e30 when no work)
    const int base = T * NCH + chunk;
#pragma unroll
    for (int rg = 0; rg < 2; ++rg)
#pragma unroll
      for (int c2 = 0; c2 < 8; ++c2)
#pragma unroll
        for (int i = 0; i < 4; ++i) {
          int row = wid * 32 + rg * 16 + g4 * 4 + i;
          part_o[((size_t)base * QTR + row) * HD + c2 * 16 + cl] = f2bf(o_acc[rg][c2][i]);
        }

#pragma unroll
    for (int rg = 0; rg < 2; ++rg)
#pragma unroll
      for (int i = 0; i < 4; ++i) {
        float lv = l_i[rg][i];
        lv += __shfl_xor(lv, 1);
        lv += __shfl_xor(lv, 2);
        lv += __shfl_xor(lv, 4);
        lv += __shfl_xor(lv, 8);
        if (cl == 0) {
          int row = wid * 32 + rg * 16 + g4 * 4 + i;
          part_ml[base * 512 + row]       = m_i[rg][i];
          part_ml[base * 512 + 256 + row] = lv;
        }
      }
  }
}

// ---------------- merge the 16 column-chunk partials (bf16 part_o) ----------------
__global__ __launch_bounds__(128)
void merge_kernel(const unsigned short* __restrict__ part_o, const float* __restrict__ part_ml,
                  float* __restrict__ out)
{
  const int row = blockIdx.x;
  const int T   = row >> 8;       // 32 tiles of 256 rows
  const int r   = row & 255;
  const int c   = threadIdx.x;

  float m[NCH], l[NCH];
  float mstar = -3e38f;
#pragma unroll
  for (int s = 0; s < NCH; ++s) {
    m[s] = part_ml[(T * NCH + s) * 512 + r];
    l[s] = part_ml[(T * NCH + s) * 512 + 256 + r];
    mstar = fmaxf(mstar, m[s]);
  }
  float num = 0.f, den = 0.f;
#pragma unroll
  for (int s = 0; s < NCH; ++s) {
    float wgt = __expf(m[s] - mstar);
    den += l[s] * wgt;
    num += wgt * bf2f(part_o[((size_t)(T * NCH + s) * QTR + r) * HD + c]);
  }
  out[(size_t)row * HD + c] = num / den;
}

extern "C" void kernel_launch(void* const* d_in, const int* in_sizes, int n_in,
                              void* d_out, int out_size, void* d_ws, size_t ws_size,
                              hipStream_t stream)
{
  const float* x  = (const float*)d_in[0];
  const float* wq = (const float*)d_in[1];
  const float* wk = (const float*)d_in[2];
  const float* wv = (const float*)d_in[3];
  float* out = (float*)d_out;

  unsigned short* p = (unsigned short*)d_ws;
  unsigned short* xh = p;  p += (size_t)S_LEN * D_DIM;       // 33.5 MB (part_o alias)
  unsigned short* xl = p;  p += (size_t)S_LEN * D_DIM;       // 33.5 MB (proj split-K partials)
  unsigned short* wTh = p; p += (size_t)3 * HD * D_DIM;
  unsigned short* wTl = p; p += (size_t)3 * HD * D_DIM;
  unsigned short* q_hi = p; p += (size_t)S_LEN * HD;
  unsigned short* q_lo = p; p += (size_t)S_LEN * HD;
  unsigned short* k_hi = p; p += (size_t)S_LEN * HD;
  unsigned short* k_lo = p; p += (size_t)S_LEN * HD;
  unsigned short* vT   = p; p += (size_t)S_LEN * HD;
  unsigned short* part_o = xh;       // 512 bases * 256 rows * 128 d, bf16 (after reduce)
  float* pp = (float*)xl;            // 6 * 8192 * 128 fp32 = 25.2 MB (dead after reduce)
  float* part_ml = (float*)wTh;      // 512 * 512 (written after proj's last wTh read)

  split_w_kernel<<<dim3(32, 3), 256, 0, stream>>>(wq, wk, wv, wTh, wTl);
  proj_sk_kernel<<<dim3(768), 256, 0, stream>>>(x, wTh, wTl, pp);
  reduce_split_kernel<<<dim3(128, 3), 256, 0, stream>>>(pp, q_hi, q_lo, k_hi, k_lo, vT);
  const int smem_bytes = (8192 * 3 + 32768 + 8 * 1280) * (int)sizeof(short);  // 135168
  attn_kernel<<<dim3(256), 512, smem_bytes, stream>>>(q_hi, q_lo, k_hi, k_lo, vT,
                                                      part_o, part_ml);
  merge_kernel<<<dim3(8192), 128, 0, stream>>>(part_o, part_ml, out);
}

// Round 19
// 129.469 us; speedup vs baseline: 1.0146x; 1.0146x over previous
//
#include <hip/hip_runtime.h>

#define S_LEN 8192
#define D_DIM 2048
#define HD    128
#define KVB   32       // kv tile rows
#define NCH   16       // kv chunks (flash-decoding split)
#define QTR   256      // q rows per block tile (8 waves x 32)

typedef __attribute__((ext_vector_type(8))) short bf16x8;
typedef __attribute__((ext_vector_type(4))) float f32x4;

__device__ __forceinline__ unsigned short f2bf(float f) {
  unsigned int u = __float_as_uint(f);
  u += 0x7fffu + ((u >> 16) & 1u);
  return (unsigned short)(u >> 16);
}
__device__ __forceinline__ float bf2f(unsigned short h) {
  return __uint_as_float(((unsigned int)h) << 16);
}

__device__ __forceinline__ void glds16(const void* g, const short* l) {
  __builtin_amdgcn_global_load_lds(
      (const __attribute__((address_space(1))) void*)g,
      (__attribute__((address_space(3))) void*)l, 16, 0, 0);
}

// ---------------- transpose+split w: wT[mode][col][k] hi/lo bf16 ----------------
__global__ __launch_bounds__(256)
void split_w_kernel(const float* __restrict__ wq, const float* __restrict__ wk,
                    const float* __restrict__ wv,
                    unsigned short* __restrict__ wTh, unsigned short* __restrict__ wTl)
{
  const int mode = blockIdx.y;
  const float* __restrict__ w = (mode == 0) ? wq : (mode == 1) ? wk : wv;
  unsigned short* __restrict__ oh = wTh + (size_t)mode * HD * D_DIM;
  unsigned short* __restrict__ ol = wTl + (size_t)mode * HD * D_DIM;
  const int k0 = blockIdx.x * 64;

  __shared__ float ws[64][132];
  const int t = threadIdx.x;
#pragma unroll
  for (int i = 0; i < 8; ++i) {
    int idx = t + i * 256;
    int row = idx >> 5;
    int c4  = idx & 31;
    *(float4*)&ws[row][c4 * 4] = *(const float4*)(w + (size_t)(k0 + row) * HD + c4 * 4);
  }
  __syncthreads();
#pragma unroll
  for (int i = 0; i < 4; ++i) {
    int task = t + i * 256;
    int col = task >> 3;
    int kc  = task & 7;
    ushort4 h[2], l[2];
#pragma unroll
    for (int e = 0; e < 8; ++e) {
      float f = ws[kc * 8 + e][col];
      unsigned short hb = f2bf(f);
      ((unsigned short*)&h[e >> 2])[e & 3] = hb;
      ((unsigned short*)&l[e >> 2])[e & 3] = f2bf(f - bf2f(hb));
    }
    size_t off = (size_t)col * D_DIM + k0 + kc * 8;
    *(ushort4*)(oh + off)     = h[0];
    *(ushort4*)(oh + off + 4) = h[1];
    *(ushort4*)(ol + off)     = l[0];
    *(ushort4*)(ol + off + 4) = l[1];
  }
}

// ---------------- projection GEMM, split-K: 64-row tiles, K halves, fp32 partials ----------------
// grid (128, 3, 2) = 768 blocks = 3/CU balanced; same per-step reuse as the r14 proj.
__global__ __launch_bounds__(256)
void proj_sk_kernel(const float* __restrict__ x,
                    const unsigned short* __restrict__ wTh, const unsigned short* __restrict__ wTl,
                    float* __restrict__ pp)
{
  __shared__ short sm[2][12288];

  const int mode = blockIdx.y;
  const int mt   = blockIdx.x;
  const int kz   = blockIdx.z;
  const bool split = (mode < 2);
  const int kbase = kz * (D_DIM / 2);

  const unsigned short* gwh = wTh + (size_t)mode * HD * D_DIM + kbase;
  const unsigned short* gwl = wTl + (size_t)mode * HD * D_DIM + kbase;

  const int t   = threadIdx.x;
  const int wid = t >> 6;
  const int ln  = t & 63;
  const int cl  = ln & 15;
  const int g4  = ln >> 4;

  const int slotx = wid * 64 + ln;          // 0..255
  const int rowx  = slotx >> 2, scx = slotx & 3;
  const int kofx  = (scx ^ (rowx & 3)) * 8;
  const float* gx = x + (size_t)(mt * 64 + rowx) * D_DIM + kbase + kofx;

  auto stagew = [&](int kt, int buf) {
    short* b = sm[buf];
#pragma unroll
    for (int g = 0; g < 2; ++g) {
      int slot = g * 256 + wid * 64 + ln;
      int col = slot >> 2, sc = slot & 3;
      int kof = (sc ^ (col & 3)) * 8;
      glds16(gwh + (size_t)col * D_DIM + kt + kof, b + 4096 + (g * 256 + wid * 64) * 8);
      if (split)
        glds16(gwl + (size_t)col * D_DIM + kt + kof, b + 8192 + (g * 256 + wid * 64) * 8);
    }
  };
  auto writex = [&](const float4& a0, const float4& a1, int buf) {
    short* b = sm[buf];
    float fv[8];
    *(float4*)&fv[0] = a0;
    *(float4*)&fv[4] = a1;
    bf16x8 hv, lv;
#pragma unroll
    for (int e = 0; e < 8; ++e) {
      unsigned short hb = f2bf(fv[e]);
      hv[e] = (short)hb;
      lv[e] = (short)f2bf(fv[e] - bf2f(hb));
    }
    *(bf16x8*)(b + slotx * 8) = hv;
    if (split) *(bf16x8*)(b + 2048 + slotx * 8) = lv;
  };

  f32x4 acc[2][4];
#pragma unroll
  for (int m = 0; m < 2; ++m)
#pragma unroll
    for (int n = 0; n < 4; ++n) acc[m][n] = f32x4{0.f, 0.f, 0.f, 0.f};

  {
    float4 a0 = *(const float4*)(gx + 0);
    float4 a1 = *(const float4*)(gx + 4);
    stagew(0, 0);
    writex(a0, a1, 0);
  }
  __syncthreads();

  const int KHALF = D_DIM / 2;
  for (int kt = 0, step = 0; kt < KHALF; kt += 32, ++step) {
    const int cur = step & 1;
    const bool more = (kt + 32 < KHALF);
    float4 n0, n1;
    if (more) {
      n0 = *(const float4*)(gx + kt + 32);
      n1 = *(const float4*)(gx + kt + 36);
      stagew(kt + 32, cur ^ 1);
    }

    const short* b = sm[cur];
    bf16x8 a_h[2], a_l[2], b_h[4], b_l[4];
#pragma unroll
    for (int m = 0; m < 2; ++m) {
      int row = (wid >> 1) * 32 + m * 16 + cl;
      int byte = row * 64 + ((g4 ^ (row & 3)) << 4);
      a_h[m] = *(const bf16x8*)((const char*)b + byte);
      if (split) a_l[m] = *(const bf16x8*)((const char*)b + 4096 + byte);
    }
#pragma unroll
    for (int n = 0; n < 4; ++n) {
      int col = (wid & 1) * 64 + n * 16 + cl;
      int byte = col * 64 + ((g4 ^ (col & 3)) << 4);
      b_h[n] = *(const bf16x8*)((const char*)b + 8192 + byte);
      if (split) b_l[n] = *(const bf16x8*)((const char*)b + 16384 + byte);
    }

#pragma unroll
    for (int m = 0; m < 2; ++m)
#pragma unroll
      for (int n = 0; n < 4; ++n)
        acc[m][n] = __builtin_amdgcn_mfma_f32_16x16x32_bf16(a_h[m], b_h[n], acc[m][n], 0, 0, 0);
    if (split) {
#pragma unroll
      for (int m = 0; m < 2; ++m)
#pragma unroll
        for (int n = 0; n < 4; ++n) {
          acc[m][n] = __builtin_amdgcn_mfma_f32_16x16x32_bf16(a_l[m], b_h[n], acc[m][n], 0, 0, 0);
          acc[m][n] = __builtin_amdgcn_mfma_f32_16x16x32_bf16(a_h[m], b_l[n], acc[m][n], 0, 0, 0);
        }
    }
    if (more) writex(n0, n1, cur ^ 1);
    __syncthreads();
  }

  // fp32 partial to pp[(mode*2 + kz)][row][col]
  const int rbase = mt * 64 + (wid >> 1) * 32 + g4 * 4;
  const int cbase = (wid & 1) * 64 + cl;
  float* op = pp + ((size_t)(mode * 2 + kz)) * S_LEN * HD;
#pragma unroll
  for (int m = 0; m < 2; ++m)
#pragma unroll
    for (int n = 0; n < 4; ++n)
#pragma unroll
      for (int r = 0; r < 4; ++r)
        op[(size_t)(rbase + m * 16 + r) * HD + cbase + n * 16] = acc[m][n][r];
}

// ---------------- reduce split-K partials + split/scale/transpose epilogue ----------------
// grid (128, 3), 256 threads; block = one 64-row tile of one mode.
__global__ __launch_bounds__(256)
void reduce_split_kernel(const float* __restrict__ pp,
                         unsigned short* __restrict__ q_hi, unsigned short* __restrict__ q_lo,
                         unsigned short* __restrict__ k_hi, unsigned short* __restrict__ k_lo,
                         unsigned short* __restrict__ vT)
{
  __shared__ float tile[64][132];
  const int mode = blockIdx.y;
  const int mt   = blockIdx.x;
  const int t    = threadIdx.x;

  const float* p0 = pp + ((size_t)(mode * 2 + 0)) * S_LEN * HD + (size_t)mt * 64 * HD;
  const float* p1 = pp + ((size_t)(mode * 2 + 1)) * S_LEN * HD + (size_t)mt * 64 * HD;

  if (mode < 2) {
    const float scale = (mode == 0) ? 0.08838834764831843f : 1.0f;
    unsigned short* __restrict__ oh = (mode == 0) ? q_hi : k_hi;
    unsigned short* __restrict__ ol = (mode == 0) ? q_lo : k_lo;
#pragma unroll
    for (int i = 0; i < 8; ++i) {
      int off = i * 1024 + t * 4;
      float4 a = *(const float4*)(p0 + off);
      float4 b = *(const float4*)(p1 + off);
      ushort4 hv, lv;
#pragma unroll
      for (int e = 0; e < 4; ++e) {
        float s = (((const float*)&a)[e] + ((const float*)&b)[e]) * scale;
        unsigned short hb = f2bf(s);
        ((unsigned short*)&hv)[e] = hb;
        ((unsigned short*)&lv)[e] = f2bf(s - bf2f(hb));
      }
      int row = off >> 7, col = off & 127;
      size_t go = (size_t)(mt * 64 + row) * HD + col;
      *(ushort4*)(oh + go) = hv;
      *(ushort4*)(ol + go) = lv;
    }
  } else {
#pragma unroll
    for (int i = 0; i < 8; ++i) {
      int off = i * 1024 + t * 4;
      float4 a = *(const float4*)(p0 + off);
      float4 b = *(const float4*)(p1 + off);
      int row = off >> 7, col = off & 127;
      float4 s;
      s.x = a.x + b.x; s.y = a.y + b.y; s.z = a.z + b.z; s.w = a.w + b.w;
      *(float4*)&tile[row][col] = s;
    }
    __syncthreads();
    const int col = t >> 1, half = t & 1;
#pragma unroll
    for (int r8 = 0; r8 < 4; ++r8) {
      bf16x8 v;
#pragma unroll
      for (int e = 0; e < 8; ++e)
        v[e] = (short)f2bf(tile[half * 32 + r8 * 8 + e][col]);
      *(bf16x8*)(vT + (size_t)col * S_LEN + mt * 64 + half * 32 + r8 * 8) = v;
    }
  }
}

// ---------------- MFMA flash attention v6b: 8-wave block, Q-lo in LDS ----------------
__global__ __launch_bounds__(512)
void attn_kernel(const unsigned short* __restrict__ q_hi, const unsigned short* __restrict__ q_lo,
                 const unsigned short* __restrict__ k_hi, const unsigned short* __restrict__ k_lo,
                 const unsigned short* __restrict__ vT,
                 unsigned short* __restrict__ part_o, float* __restrict__ part_ml)
{
  extern __shared__ short smem[];
  short* ls_kh = smem;               // 2 x 4096: K hi 32x128, swizzled (sc ^ row&7)
  short* ls_kl = ls_kh + 8192;       // 2 x 4096: K lo
  short* ls_v  = ls_kl + 8192;       // 2 x 4096: v^T 128x32, swizzled (sub ^ (d>>1)&3)
  short* ls_ql = ls_v + 8192;        // 256 x 128: Q lo tile, swizzled like K
  short* ls_p  = ls_ql + 32768;      // 8 waves x [32][40]

  const int t   = threadIdx.x;
  const int wid = t >> 6;            // 0..7
  const int ln  = t & 63;
  const int cl  = ln & 15;
  const int g4  = ln >> 4;
  const int pairId = blockIdx.x >> 4;   // 0..15
  const int chunk  = blockIdx.x & 15;

  short* pw = ls_p + wid * 1280;

  auto stage = [&](int j, int buf) {
    const unsigned short* gkh = k_hi + (size_t)j * KVB * HD;
    const unsigned short* gkl = k_lo + (size_t)j * KVB * HD;
    const unsigned short* gv  = vT + (size_t)j * KVB;
    {
      int row = t >> 4, sc = t & 15;          // 512 slots = 32 rows x 16
      int c16 = sc ^ (row & 7);
      glds16(gkh + row * HD + c16 * 8, ls_kh + buf * 4096 + t * 8);
      glds16(gkl + row * HD + c16 * 8, ls_kl + buf * 4096 + t * 8);
    }
    {
      int d = t >> 2, sub = t & 3;            // 512 slots = 128 d x 4
      int s2 = sub ^ ((d >> 1) & 3);
      glds16(gv + (size_t)d * S_LEN + s2 * 8, ls_v + buf * 4096 + t * 8);
    }
  };

  for (int hh = 0; hh < 2; ++hh) {
    const int T = hh ? (31 - pairId) : pairId;
    const int jmaxB = 8 * T + 7;
    const int jmaxW = 8 * T + wid;
    const int rowbase = T * QTR + wid * 32;

    // stage Q-lo tile (256x128 bf16, 64KB); consumed only after the in-loop barrier
    {
      const unsigned short* gql = q_lo + (size_t)T * QTR * HD;
#pragma unroll
      for (int i = 0; i < 8; ++i) {
        int slot = i * 512 + t;
        int row = slot >> 4, sc = slot & 15;
        int c16 = sc ^ (row & 7);
        glds16(gql + (size_t)row * HD + c16 * 8, ls_ql + slot * 8);
      }
    }

    // Q-hi fragments in registers (A-layout: row = rg*16 + cl, k = kc*32 + g4*8 + e)
    bf16x8 qh[2][4];
#pragma unroll
    for (int rg = 0; rg < 2; ++rg) {
      const size_t qoff = ((size_t)rowbase + rg * 16 + cl) * HD + g4 * 8;
#pragma unroll
      for (int kc = 0; kc < 4; ++kc)
        qh[rg][kc] = *(const bf16x8*)(q_hi + qoff + kc * 32);
    }

    float m_i[2][4], l_i[2][4];
    f32x4 o_acc[2][8];
#pragma unroll
    for (int rg = 0; rg < 2; ++rg)
#pragma unroll
      for (int i = 0; i < 4; ++i) { m_i[rg][i] = -1e30f; l_i[rg][i] = 0.f; }
#pragma unroll
    for (int rg = 0; rg < 2; ++rg)
#pragma unroll
      for (int c2 = 0; c2 < 8; ++c2) o_acc[rg][c2] = f32x4{0.f, 0.f, 0.f, 0.f};

    if (chunk <= jmaxB) {
      int cur = 0;
      stage(chunk, 0);
      __syncthreads();
      for (int j = chunk; j <= jmaxB; j += NCH) {
        if (j + NCH <= jmaxB) stage(j + NCH, cur ^ 1);

        if (j <= jmaxW) {
          const int rl0 = wid * 32 + cl;       // local tile row, rg = 0
          const int rl1 = rl0 + 16;            // rg = 1 (same &7 as rl0)
          // ---- QK^T: 3-product split (hh + lh + hl); Q-lo frags from LDS
          f32x4 s[2][2];
          s[0][0] = f32x4{0.f, 0.f, 0.f, 0.f};
          s[0][1] = f32x4{0.f, 0.f, 0.f, 0.f};
          s[1][0] = f32x4{0.f, 0.f, 0.f, 0.f};
          s[1][1] = f32x4{0.f, 0.f, 0.f, 0.f};
          __builtin_amdgcn_s_setprio(1);
#pragma unroll
          for (int kc = 0; kc < 4; ++kc) {
            const int ch = kc * 4 + g4;
            bf16x8 ql0 = *(const bf16x8*)((const char*)ls_ql + rl0 * 256 + ((ch ^ (rl0 & 7)) << 4));
            bf16x8 ql1 = *(const bf16x8*)((const char*)ls_ql + rl1 * 256 + ((ch ^ (rl1 & 7)) << 4));
#pragma unroll
            for (int c = 0; c < 2; ++c) {
              const int kcol = c * 16 + cl;
              const int byteK = kcol * 256 + ((ch ^ (kcol & 7)) << 4);
              bf16x8 khf = *(const bf16x8*)((const char*)(ls_kh + cur * 4096) + byteK);
              bf16x8 klf = *(const bf16x8*)((const char*)(ls_kl + cur * 4096) + byteK);
              s[0][c] = __builtin_amdgcn_mfma_f32_16x16x32_bf16(qh[0][kc], khf, s[0][c], 0, 0, 0);
              s[0][c] = __builtin_amdgcn_mfma_f32_16x16x32_bf16(ql0,      khf, s[0][c], 0, 0, 0);
              s[0][c] = __builtin_amdgcn_mfma_f32_16x16x32_bf16(qh[0][kc], klf, s[0][c], 0, 0, 0);
              s[1][c] = __builtin_amdgcn_mfma_f32_16x16x32_bf16(qh[1][kc], khf, s[1][c], 0, 0, 0);
              s[1][c] = __builtin_amdgcn_mfma_f32_16x16x32_bf16(ql1,      khf, s[1][c], 0, 0, 0);
              s[1][c] = __builtin_amdgcn_mfma_f32_16x16x32_bf16(qh[1][kc], klf, s[1][c], 0, 0, 0);
            }
          }
          __builtin_amdgcn_s_setprio(0);

          // causal mask: only the wave's diagonal kv tile crosses row boundaries
          if (j == jmaxW) {
#pragma unroll
            for (int rg = 0; rg < 2; ++rg)
#pragma unroll
              for (int c = 0; c < 2; ++c)
#pragma unroll
                for (int i = 0; i < 4; ++i) {
                  int col = j * KVB + c * 16 + cl;
                  int row = rowbase + rg * 16 + g4 * 4 + i;
                  if (col > row) s[rg][c][i] = -1e30f;
                }
          }

          // ---- defer-max online softmax (shuffle-free steady state)
          bool ok = true;
#pragma unroll
          for (int rg = 0; rg < 2; ++rg)
#pragma unroll
            for (int i = 0; i < 4; ++i) {
              float mx = fmaxf(s[rg][0][i], s[rg][1][i]);
              ok = ok && (mx <= m_i[rg][i] + 8.0f);
            }
          if (!__all(ok)) {
#pragma unroll
            for (int rg = 0; rg < 2; ++rg)
#pragma unroll
              for (int i = 0; i < 4; ++i) {
                float rm = fmaxf(s[rg][0][i], s[rg][1][i]);
                rm = fmaxf(rm, __shfl_xor(rm, 1));
                rm = fmaxf(rm, __shfl_xor(rm, 2));
                rm = fmaxf(rm, __shfl_xor(rm, 4));
                rm = fmaxf(rm, __shfl_xor(rm, 8));
                float mnew = fmaxf(m_i[rg][i], rm);
                float corr = __expf(m_i[rg][i] - mnew);
                l_i[rg][i] *= corr;
#pragma unroll
                for (int c2 = 0; c2 < 8; ++c2) o_acc[rg][c2][i] *= corr;
                m_i[rg][i] = mnew;
              }
          }

          // p = exp(s - m) (0 for masked), lane-partial l, P -> wave LDS (bf16)
#pragma unroll
          for (int rg = 0; rg < 2; ++rg)
#pragma unroll
            for (int c = 0; c < 2; ++c)
#pragma unroll
              for (int i = 0; i < 4; ++i) {
                float sv = s[rg][c][i];
                float p = (sv > -1e29f) ? __expf(sv - m_i[rg][i]) : 0.f;
                l_i[rg][i] += p;
                pw[(rg * 16 + g4 * 4 + i) * 40 + c * 16 + cl] = (short)f2bf(p);
              }

          // ---- PV: o += P @ V (A-frags from wave LDS, B-frags = vT rows, shared by rg)
          bf16x8 pa0 = *(const bf16x8*)((const char*)pw + cl * 80 + g4 * 16);
          bf16x8 pa1 = *(const bf16x8*)((const char*)pw + (16 + cl) * 80 + g4 * 16);
          __builtin_amdgcn_s_setprio(1);
#pragma unroll
          for (int c2 = 0; c2 < 8; ++c2) {
            const int d0 = c2 * 16 + cl;
            const int byteV = d0 * 64 + ((g4 ^ ((d0 >> 1) & 3)) << 4);
            bf16x8 vb = *(const bf16x8*)((const char*)(ls_v + cur * 4096) + byteV);
            o_acc[0][c2] = __builtin_amdgcn_mfma_f32_16x16x32_bf16(pa0, vb, o_acc[0][c2], 0, 0, 0);
            o_acc[1][c2] = __builtin_amdgcn_mfma_f32_16x16x32_bf16(pa1, vb, o_acc[1][c2], 0, 0, 0);
          }
          __builtin_amdgcn_s_setprio(0);
        }

        __syncthreads();
        cur ^= 1;
      }
    }

    // ---- write partials as bf16 (unconditional; zeros + m=-1e30 when no work)
    const int base = T * NCH + chunk;
#pragma unroll
    for (int rg = 0; rg < 2; ++rg)
#pragma unroll
      for (int c2 = 0; c2 < 8; ++c2)
#pragma unroll
        for (int i = 0; i < 4; ++i) {
          int row = wid * 32 + rg * 16 + g4 * 4 + i;
          part_o[((size_t)base * QTR + row) * HD + c2 * 16 + cl] = f2bf(o_acc[rg][c2][i]);
        }

#pragma unroll
    for (int rg = 0; rg < 2; ++rg)
#pragma unroll
      for (int i = 0; i < 4; ++i) {
        float lv = l_i[rg][i];
        lv += __shfl_xor(lv, 1);
        lv += __shfl_xor(lv, 2);
        lv += __shfl_xor(lv, 4);
        lv += __shfl_xor(lv, 8);
        if (cl == 0) {
          int row = wid * 32 + rg * 16 + g4 * 4 + i;
          part_ml[base * 512 + row]       = m_i[rg][i];
          part_ml[base * 512 + 256 + row] = lv;
        }
      }
  }
}

// ---------------- merge the 16 column-chunk partials (bf16 part_o) ----------------
__global__ __launch_bounds__(128)
void merge_kernel(const unsigned short* __restrict__ part_o, const float* __restrict__ part_ml,
                  float* __restrict__ out)
{
  const int row = blockIdx.x;
  const int T   = row >> 8;       // 32 tiles of 256 rows
  const int r   = row & 255;
  const int c   = threadIdx.x;

  float m[NCH], l[NCH];
  float mstar = -3e38f;
#pragma unroll
  for (int s = 0; s < NCH; ++s) {
    m[s] = part_ml[(T * NCH + s) * 512 + r];
    l[s] = part_ml[(T * NCH + s) * 512 + 256 + r];
    mstar = fmaxf(mstar, m[s]);
  }
  float num = 0.f, den = 0.f;
#pragma unroll
  for (int s = 0; s < NCH; ++s) {
    float wgt = __expf(m[s] - mstar);
    den += l[s] * wgt;
    num += wgt * bf2f(part_o[((size_t)(T * NCH + s) * QTR + r) * HD + c]);
  }
  out[(size_t)row * HD + c] = num / den;
}

extern "C" void kernel_launch(void* const* d_in, const int* in_sizes, int n_in,
                              void* d_out, int out_size, void* d_ws, size_t ws_size,
                              hipStream_t stream)
{
  const float* x  = (const float*)d_in[0];
  const float* wq = (const float*)d_in[1];
  const float* wk = (const float*)d_in[2];
  const float* wv = (const float*)d_in[3];
  float* out = (float*)d_out;

  unsigned short* p = (unsigned short*)d_ws;
  unsigned short* xh = p;  p += (size_t)S_LEN * D_DIM;       // 33.5 MB (part_o alias)
  unsigned short* xl = p;  p += (size_t)S_LEN * D_DIM;       // 33.5 MB (proj split-K partials)
  unsigned short* wTh = p; p += (size_t)3 * HD * D_DIM;
  unsigned short* wTl = p; p += (size_t)3 * HD * D_DIM;
  unsigned short* q_hi = p; p += (size_t)S_LEN * HD;
  unsigned short* q_lo = p; p += (size_t)S_LEN * HD;
  unsigned short* k_hi = p; p += (size_t)S_LEN * HD;
  unsigned short* k_lo = p; p += (size_t)S_LEN * HD;
  unsigned short* vT   = p; p += (size_t)S_LEN * HD;
  unsigned short* part_o = xh;       // 512 bases * 256 rows * 128 d, bf16 (after reduce)
  float* pp = (float*)xl;            // 6 * 8192 * 128 fp32 = 25.2 MB (dead after reduce)
  float* part_ml = (float*)wTh;      // 512 * 512 (written after proj's last wTh read)

  split_w_kernel<<<dim3(32, 3), 256, 0, stream>>>(wq, wk, wv, wTh, wTl);
  proj_sk_kernel<<<dim3(128, 3, 2), 256, 0, stream>>>(x, wTh, wTl, pp);
  reduce_split_kernel<<<dim3(128, 3), 256, 0, stream>>>(pp, q_hi, q_lo, k_hi, k_lo, vT);
  const int smem_bytes = (8192 * 3 + 32768 + 8 * 1280) * (int)sizeof(short);  // 135168
  attn_kernel<<<dim3(256), 512, smem_bytes, stream>>>(q_hi, q_lo, k_hi, k_lo, vT,
                                                      part_o, part_ml);
  merge_kernel<<<dim3(8192), 128, 0, stream>>>(part_o, part_ml, out);
}